// Round 12
// baseline (223.739 us; speedup 1.0000x reference)
//
#include <hip/hip_runtime.h>
#include <hip/hip_bf16.h>
#include <hip/hip_cooperative_groups.h>
#include <stdint.h>

#define B 4
#define N 2048
#define DIN 128
#define H 4
#define HD 32
#define NEG 0.2f
#define LOG2E 1.4426950408889634f
#define WINJ 256

typedef __attribute__((ext_vector_type(8))) short short8;
typedef __attribute__((ext_vector_type(4))) float f32x4;

// VT layout: [bh][d][window(8) | swizzled slot(32) | elem(8)] bf16, slot = gw ^ (d&7).
// bitsT layout: [jword(32)][row(2048)] u64 — one coalesced 128B mask load per wave/window.

// ================= FUSED COOPERATIVE KERNEL =================
// grid 512 x 256 (2 blocks/CU, co-resident). Phase A: gemm tile + pack slice.
// grid.sync(). Phase B: windowed LDS-dbuf MFMA attention (r11 structure).
__global__ __launch_bounds__(256) void k_all(const float* __restrict__ x,
                                             const float* __restrict__ W,
                                             const float* __restrict__ a,
                                             const int* __restrict__ adj,
                                             unsigned short* __restrict__ VT,
                                             float* __restrict__ ei_t,
                                             float* __restrict__ ej_t,
                                             unsigned long long* __restrict__ bitsT,
                                             float* __restrict__ out) {
    __shared__ __align__(16) char smem[37888];   // union: gemm 37KB / attn 34KB

    const int tid = threadIdx.x;
    const int bid = blockIdx.x;
    const int lane = tid & 63;

    // ---------- Phase A1: adjacency pack (grid-strided slice) ----------
    {
#pragma unroll 4
        for (int i = 0; i < 32; ++i) {
            int t = (bid * 32 + i) * 256 + tid;
            int v = adj[t];
            unsigned long long m = __ballot(v != 0);
            if ((tid & 63) == 0) {
                int row = t >> 11, jw = (t >> 6) & 31;
                bitsT[(size_t)jw * 2048 + row] = m;
            }
        }
    }

    // ---------- Phase A2: gemm tile (16 rows) -> swizzled VT + ei/ej ----------
    {
        float (*Wt0)[64] = (float(*)[64])smem;              // 16KB
        float (*Wt1)[64] = (float(*)[64])(smem + 16384);    // 16KB
        float (*xT)[20]  = (float(*)[20])(smem + 32768);    // 5KB

        const int r0 = (tid >> 6) * 4;
        const int c2 = lane;
        const int rowBase = bid * 16;
        float acc[4][2];
#pragma unroll
        for (int i = 0; i < 4; ++i) { acc[i][0] = 0.f; acc[i][1] = 0.f; }

        for (int kh = 0; kh < 2; ++kh) {
            __syncthreads();
            {   // stage W half, even/odd col planes (conflict-free)
                const int c = tid & 127;
                const int qb = (tid >> 7) * 8;
                const int ci = c >> 1, pl = c & 1;
                const float4* W4 = (const float4*)W;
#pragma unroll
                for (int q = 0; q < 8; ++q) {
                    float4 v = W4[c * 32 + kh * 16 + qb + q];
                    int kk = (qb + q) * 4;
                    if (pl == 0) {
                        Wt0[kk + 0][ci] = v.x; Wt0[kk + 1][ci] = v.y;
                        Wt0[kk + 2][ci] = v.z; Wt0[kk + 3][ci] = v.w;
                    } else {
                        Wt1[kk + 0][ci] = v.x; Wt1[kk + 1][ci] = v.y;
                        Wt1[kk + 2][ci] = v.z; Wt1[kk + 3][ci] = v.w;
                    }
                }
            }
            {   // stage x
                const int rl = tid >> 4;
                const int q = tid & 15;
                float4 v = ((const float4*)x)[(rowBase + rl) * 32 + kh * 16 + q];
                int kk = q * 4;
                xT[kk + 0][rl] = v.x; xT[kk + 1][rl] = v.y;
                xT[kk + 2][rl] = v.z; xT[kk + 3][rl] = v.w;
            }
            __syncthreads();
#pragma unroll 8
            for (int kk = 0; kk < 64; ++kk) {
                float w0 = Wt0[kk][c2];
                float w1 = Wt1[kk][c2];
#pragma unroll
                for (int i = 0; i < 4; ++i) {
                    float xv = xT[kk][r0 + i];
                    acc[i][0] += xv * w0;
                    acc[i][1] += xv * w1;
                }
            }
        }

        const int c0 = 2 * c2;
        const int headT = c0 >> 5, d0 = c0 & 31;
        const int b = rowBase >> 11;
        const int n0 = (rowBase & 2047) + r0;
        const int bh = b * 4 + headT;

        {   // V^T bf16, PRE-SWIZZLED within 256-j window: slot = gw ^ (d&7)
            ushort4 p0, p1;
            unsigned short* q0 = (unsigned short*)&p0;
            unsigned short* q1 = (unsigned short*)&p1;
#pragma unroll
            for (int i = 0; i < 4; ++i) {
                __hip_bfloat16 h0 = __float2bfloat16(acc[i][0]);
                __hip_bfloat16 h1 = __float2bfloat16(acc[i][1]);
                q0[i] = *(unsigned short*)&h0;
                q1[i] = *(unsigned short*)&h1;
            }
            const int wdw = n0 >> 8;
            const int gw  = (n0 >> 3) & 31;
            const int off = n0 & 7;
            const int gs0 = gw ^ (d0 & 7);
            const int gs1 = gw ^ ((d0 + 1) & 7);
            *(ushort4*)&VT[((size_t)bh * 32 + d0) * 2048 + wdw * WINJ + gs0 * 8 + off] = p0;
            *(ushort4*)&VT[((size_t)bh * 32 + d0 + 1) * 2048 + wdw * WINJ + gs1 * 8 + off] = p1;
        }
        {   // ei/ej (log2e-scaled)
            float a10 = a[headT * 64 + d0],      a11 = a[headT * 64 + d0 + 1];
            float a20 = a[headT * 64 + 32 + d0], a21 = a[headT * 64 + 32 + d0 + 1];
#pragma unroll
            for (int i = 0; i < 4; ++i) {
                float pi = acc[i][0] * a10 + acc[i][1] * a11;
                float pj = acc[i][0] * a20 + acc[i][1] * a21;
#pragma unroll
                for (int off = 1; off < 16; off <<= 1) {
                    pi += __shfl_xor(pi, off);
                    pj += __shfl_xor(pj, off);
                }
                if ((lane & 15) == 0) {
                    ei_t[(size_t)bh * 2048 + n0 + i] = pi * LOG2E;
                    ej_t[(size_t)bh * 2048 + n0 + i] = pj * LOG2E;
                }
            }
        }
    }

    // ---------- grid-wide barrier ----------
    __threadfence();
    cooperative_groups::this_grid().sync();
    __syncthreads();

    // ---------- Phase B: windowed LDS-dbuf MFMA attention ----------
    {
        unsigned short (*Vs)[32 * WINJ] = (unsigned short(*)[32 * WINJ])smem;  // 2x16KB
        float (*ejs)[WINJ] = (float(*)[WINJ])(smem + 32768);                   // 2x1KB

        const int rt = bid & 31;
        const int head = (bid >> 5) & 3;
        const int b = bid >> 7;
        const int wv = tid >> 6;
        const int lr = lane & 15;
        const int g = lane >> 4;
        const int rowW = rt * 64 + wv * 16;
        const int bh = b * 4 + head;

        const unsigned short* VTb = VT + (size_t)bh * 32 * 2048;
        const float* ejg = ej_t + (size_t)bh * 2048;
        const float eir = ei_t[(size_t)bh * 2048 + rowW + lr];

        f32x4 acc0 = {0.f, 0.f, 0.f, 0.f};
        f32x4 acc1 = {0.f, 0.f, 0.f, 0.f};
        f32x4 accS = {0.f, 0.f, 0.f, 0.f};
        short8 onesb;
        {
            short ov = (lr == 0) ? (short)0x3F80 : (short)0;   // bf16 1.0 in col 0
#pragma unroll
            for (int e = 0; e < 8; ++e) onesb[e] = ov;
        }

        // prologue: stage window 0
        {
#pragma unroll
            for (int i = 0; i < 4; ++i) {
                int L = i * 256 + tid, d = L >> 5, gr = L & 31;
                float4 v = *(const float4*)&VTb[(size_t)d * 2048 + gr * 8];
                *(float4*)&Vs[0][(size_t)L * 8] = v;
            }
            if (tid < 64) {
                float4 e = *(const float4*)&ejg[tid * 4];
                *(float4*)&ejs[0][tid * 4] = e;
            }
        }
        __syncthreads();

        for (int w = 0; w < 8; ++w) {
            const int buf = w & 1;
            const unsigned long long wreg =
                bitsT[(size_t)(w * 4 + g) * 2048 + rowW + lr];

            float4 vr0, vr1, vr2, vr3, er;
            const bool pf = (w < 7);
            if (pf) {   // issue next-window loads EARLY
                const unsigned short* src = VTb + (w + 1) * WINJ;
                vr0 = *(const float4*)&src[(size_t)((tid)       >> 5) * 2048 + ((tid)       & 31) * 8];
                vr1 = *(const float4*)&src[(size_t)((256 + tid) >> 5) * 2048 + ((256 + tid) & 31) * 8];
                vr2 = *(const float4*)&src[(size_t)((512 + tid) >> 5) * 2048 + ((512 + tid) & 31) * 8];
                vr3 = *(const float4*)&src[(size_t)((768 + tid) >> 5) * 2048 + ((768 + tid) & 31) * 8];
                if (tid < 64) er = *(const float4*)&ejg[(w + 1) * WINJ + tid * 4];
            }
            __builtin_amdgcn_sched_barrier(0);   // pin load issue before compute

            const unsigned short* Vb = &Vs[buf][0];
            const float* ejb = &ejs[buf][0];
#pragma unroll
            for (int jl = 0; jl < WINJ; jl += 64) {
                const unsigned long long word = __shfl(wreg, (jl >> 6) * 16 + lr);
#pragma unroll
                for (int ks = 0; ks < 2; ++ks) {
                    const int gw_ = (jl >> 3) + ks * 4 + g;
                    const int slot = gw_ ^ (lr & 7);
                    short8 b0 = *(const short8*)&Vb[lr * WINJ + slot * 8];
                    short8 b1 = *(const short8*)&Vb[(16 + lr) * WINJ + slot * 8];
                    const int f = jl + ks * 32 + g * 8;
                    float4 ea = *(const float4*)&ejb[f];
                    float4 eb = *(const float4*)&ejb[f + 4];
                    const unsigned int mb =
                        (unsigned int)(word >> (ks * 32 + g * 8)) & 0xffu;
                    float ej8[8] = {ea.x, ea.y, ea.z, ea.w, eb.x, eb.y, eb.z, eb.w};
                    short8 pa;
#pragma unroll
                    for (int e = 0; e < 8; ++e) {
                        float s = eir + ej8[e];
                        float el = fmaxf(s, NEG * s);
                        float p = ((mb >> e) & 1u) ? __builtin_amdgcn_exp2f(el) : 0.f;
                        __hip_bfloat16 pb = __float2bfloat16(p);
                        pa[e] = (short)*(unsigned short*)&pb;
                    }
                    __builtin_amdgcn_s_setprio(1);
                    acc0 = __builtin_amdgcn_mfma_f32_16x16x32_bf16(pa, b0, acc0, 0, 0, 0);
                    acc1 = __builtin_amdgcn_mfma_f32_16x16x32_bf16(pa, b1, acc1, 0, 0, 0);
                    accS = __builtin_amdgcn_mfma_f32_16x16x32_bf16(pa, onesb, accS, 0, 0, 0);
                    __builtin_amdgcn_s_setprio(0);
                }
            }

            if (pf) {   // write-late into the other buffer
                const int nbuf = buf ^ 1;
                *(float4*)&Vs[nbuf][(size_t)tid * 8]         = vr0;
                *(float4*)&Vs[nbuf][(size_t)(256 + tid) * 8] = vr1;
                *(float4*)&Vs[nbuf][(size_t)(512 + tid) * 8] = vr2;
                *(float4*)&Vs[nbuf][(size_t)(768 + tid) * 8] = vr3;
                if (tid < 64) *(float4*)&ejs[nbuf][tid * 4] = er;
            }
            __syncthreads();
        }

        // epilogue: rowsum from ones-MFMA col0, normalize, store
        // C/D layout (HW-verified): col = lane&15, row = 4*(lane>>4)+reg.
#pragma unroll
        for (int reg = 0; reg < 4; ++reg) {
            const float sr = __shfl(accS[reg], g * 16);
            const float inv = 1.f / sr;
            const int m = 4 * g + reg;
            float* dst = &out[(size_t)(b * N + rowW + m) * 128 + head * 32 + lr];
            dst[0]  = acc0[reg] * inv;
            dst[16] = acc1[reg] * inv;
        }
    }
}

// ================= FALLBACK: ZERO-WORKSPACE FUSED KERNEL =================
__global__ __launch_bounds__(256) void k_fused(const float* __restrict__ x,
                                               const int* __restrict__ adj,
                                               const float* __restrict__ W,
                                               const float* __restrict__ a,
                                               float* __restrict__ out) {
    __shared__ float Ws[32][129];
    __shared__ float xs[64][132];
    __shared__ float hs[64][44];
    __shared__ float ejs[64];
    __shared__ float eis[128];
    __shared__ float a1s[32], a2s[32];
    __shared__ unsigned long long mb[128];

    const int tid = threadIdx.x;
    const int bid = blockIdx.x;
    const int rt = bid & 15;
    const int head = (bid >> 4) & 3;
    const int b = bid >> 6;
    const int row0 = rt * 128;

    for (int idx = tid; idx < 32 * 128; idx += 256) {
        int d = idx >> 7, k = idx & 127;
        Ws[d][k] = W[(head * 32 + d) * 128 + k];
    }
    if (tid < 32) a1s[tid] = a[head * 64 + tid];
    else if (tid < 64) a2s[tid - 32] = a[head * 64 + tid];
    __syncthreads();

    for (int c0 = 0; c0 < 128; c0 += 64) {
        __syncthreads();
        {
            int jj = tid >> 2, k0 = (tid & 3) * 32;
            const float4* src = (const float4*)&x[(b * N + row0 + c0 + jj) * 128 + k0];
#pragma unroll
            for (int q = 0; q < 8; ++q) *(float4*)&xs[jj][k0 + q * 4] = src[q];
        }
        __syncthreads();
        {
            int jj = tid >> 2, db = (tid & 3) * 8;
#pragma unroll
            for (int dd = 0; dd < 8; ++dd) {
                float s = 0.f;
                for (int k = 0; k < 128; ++k) s += xs[jj][k] * Ws[db + dd][k];
                hs[jj][db + dd] = s;
            }
        }
        __syncthreads();
        if (tid < 64) {
            float s = 0.f;
#pragma unroll
            for (int d = 0; d < 32; ++d) s += hs[tid][d] * a1s[d];
            eis[c0 + tid] = s;
        }
    }

    const int dgrp = tid & 3, d0 = dgrp * 8;
    const int rseg = tid >> 2;
    float acc[2][8];
    float sacc[2] = {0.f, 0.f};
#pragma unroll
    for (int k = 0; k < 2; ++k)
#pragma unroll
        for (int d = 0; d < 8; ++d) acc[k][d] = 0.f;

    for (int jc = 0; jc < N; jc += 64) {
        __syncthreads();
        {
            int jj = tid >> 2, k0 = (tid & 3) * 32;
            const float4* src = (const float4*)&x[(b * N + jc + jj) * 128 + k0];
#pragma unroll
            for (int q = 0; q < 8; ++q) *(float4*)&xs[jj][k0 + q * 4] = src[q];
        }
        {
            int wv = tid >> 6, lane = tid & 63;
            for (int p = 0; p < 32; ++p) {
                int il = p * 4 + wv;
                unsigned long long m = __ballot(adj[(row0 + il) * N + jc + lane] != 0);
                if (lane == 0) mb[il] = m;
            }
        }
        __syncthreads();
        {
            int jj = tid >> 2, db = (tid & 3) * 8;
#pragma unroll
            for (int dd = 0; dd < 8; ++dd) {
                float s = 0.f;
                for (int k = 0; k < 128; ++k) s += xs[jj][k] * Ws[db + dd][k];
                hs[jj][db + dd] = s;
            }
        }
        __syncthreads();
        if (tid < 64) {
            float s = 0.f;
#pragma unroll
            for (int d = 0; d < 32; ++d) s += hs[tid][d] * a2s[d];
            ejs[tid] = s;
        }
        __syncthreads();
        for (int jj = 0; jj < 64; ++jj) {
            float ejv = ejs[jj];
            float hv[8];
#pragma unroll
            for (int d = 0; d < 8; ++d) hv[d] = hs[jj][d0 + d];
#pragma unroll
            for (int k = 0; k < 2; ++k) {
                int il = rseg * 2 + k;
                float s = eis[il] + ejv;
                float el = s > 0.f ? s : NEG * s;
                float p = ((mb[il] >> jj) & 1ull) ? __expf(el) : 0.f;
                sacc[k] += p;
#pragma unroll
                for (int d = 0; d < 8; ++d) acc[k][d] += p * hv[d];
            }
        }
    }
#pragma unroll
    for (int k = 0; k < 2; ++k) {
        int il = rseg * 2 + k;
        float inv = 1.f / sacc[k];
        float* dst = &out[(b * N + row0 + il) * 128 + head * 32 + d0];
#pragma unroll
        for (int d = 0; d < 8; ++d) dst[d] = acc[k][d] * inv;
    }
}

extern "C" void kernel_launch(void* const* d_in, const int* in_sizes, int n_in,
                              void* d_out, int out_size, void* d_ws, size_t ws_size,
                              hipStream_t stream) {
    // Identify inputs by element count (all unique) — order-proof.
    const float* x = nullptr; const int* adj = nullptr;
    const float* W = nullptr; const float* a = nullptr;
    for (int i = 0; i < n_in; ++i) {
        switch (in_sizes[i]) {
            case B * N * DIN:  x   = (const float*)d_in[i]; break;  // 1048576
            case N * N:        adj = (const int*)d_in[i];   break;  // 4194304
            case H * HD * DIN: W   = (const float*)d_in[i]; break;  // 16384
            case H * 2 * HD:   a   = (const float*)d_in[i]; break;  // 256
        }
    }
    float* out = (float*)d_out;   // reference output dtype is float32

    // ws: VT bf16 2MB | ei_t 128KB | ej_t 128KB | bitsT 512KB  = 2.75 MB
    const size_t szVT = (size_t)B * H * HD * N * 2;
    const size_t szE  = (size_t)B * H * N * 4;
    const size_t szBits = (size_t)N * (N / 64) * 8;
    const size_t need = szVT + 2 * szE + szBits;

    if (ws_size >= need) {
        char* ws = (char*)d_ws;
        unsigned short* VT = (unsigned short*)ws;
        float* ei_t = (float*)(ws + szVT);
        float* ej_t = (float*)(ws + szVT + szE);
        unsigned long long* bitsT = (unsigned long long*)(ws + szVT + 2 * szE);

        void* kargs[] = {(void*)&x, (void*)&W, (void*)&a, (void*)&adj,
                         (void*)&VT, (void*)&ei_t, (void*)&ej_t, (void*)&bitsT,
                         (void*)&out};
        hipLaunchCooperativeKernel((void*)k_all, dim3(512), dim3(256),
                                   kargs, 0, stream);
    } else {
        k_fused<<<256, 256, 0, stream>>>(x, adj, W, a, out);
    }
}

// Round 13
// 112.228 us; speedup vs baseline: 1.9936x; 1.9936x over previous
//
#include <hip/hip_runtime.h>
#include <hip/hip_bf16.h>
#include <stdint.h>

#define B 4
#define N 2048
#define DIN 128
#define H 4
#define HD 32
#define NEG 0.2f
#define LOG2E 1.4426950408889634f
#define WINJ 256

typedef __attribute__((ext_vector_type(8))) short short8;
typedef __attribute__((ext_vector_type(4))) float f32x4;

// VT layout: [bh][d][window(8) | swizzled slot(32) | elem(8)] bf16, slot = gw ^ (d&7).
// bitsT layout: [jword(32)][row(2048)] u64.

// ---------- Kernel 1: prep = gemm (VT swizzled + ei/ej) + folded adjacency pack ----------
// 512 blocks x 256 thr; each block: 1/512 pack slice + one 16-row gemm tile.
__global__ __launch_bounds__(256) void k_prep(const float* __restrict__ x,
                                              const float* __restrict__ W,
                                              const float* __restrict__ a,
                                              const int* __restrict__ adj,
                                              unsigned short* __restrict__ VT,
                                              float* __restrict__ ei_t,
                                              float* __restrict__ ej_t,
                                              unsigned long long* __restrict__ bitsT) {
    __shared__ float Wt0[64][64];
    __shared__ float Wt1[64][64];
    __shared__ float xT[64][20];

    const int tid = threadIdx.x;
    const int bid = blockIdx.x;
    const int lane = tid & 63;

    {   // ---- pack slice (grid-strided, r12-verified) ----
#pragma unroll 4
        for (int i = 0; i < 32; ++i) {
            int t = (bid * 32 + i) * 256 + tid;
            int v = adj[t];
            unsigned long long m = __ballot(v != 0);
            if ((tid & 63) == 0) {
                int row = t >> 11, jw = (t >> 6) & 31;
                bitsT[(size_t)jw * 2048 + row] = m;
            }
        }
    }

    // ---- gemm tile ----
    const int r0 = (tid >> 6) * 4;
    const int c2 = lane;
    const int rowBase = bid * 16;
    float acc[4][2];
#pragma unroll
    for (int i = 0; i < 4; ++i) { acc[i][0] = 0.f; acc[i][1] = 0.f; }

    for (int kh = 0; kh < 2; ++kh) {
        __syncthreads();
        {   // stage W half, even/odd col planes
            const int c = tid & 127;
            const int qb = (tid >> 7) * 8;
            const int ci = c >> 1, pl = c & 1;
            const float4* W4 = (const float4*)W;
#pragma unroll
            for (int q = 0; q < 8; ++q) {
                float4 v = W4[c * 32 + kh * 16 + qb + q];
                int kk = (qb + q) * 4;
                if (pl == 0) {
                    Wt0[kk + 0][ci] = v.x; Wt0[kk + 1][ci] = v.y;
                    Wt0[kk + 2][ci] = v.z; Wt0[kk + 3][ci] = v.w;
                } else {
                    Wt1[kk + 0][ci] = v.x; Wt1[kk + 1][ci] = v.y;
                    Wt1[kk + 2][ci] = v.z; Wt1[kk + 3][ci] = v.w;
                }
            }
        }
        {   // stage x
            const int rl = tid >> 4;
            const int q = tid & 15;
            float4 v = ((const float4*)x)[(rowBase + rl) * 32 + kh * 16 + q];
            int kk = q * 4;
            xT[kk + 0][rl] = v.x; xT[kk + 1][rl] = v.y;
            xT[kk + 2][rl] = v.z; xT[kk + 3][rl] = v.w;
        }
        __syncthreads();
#pragma unroll 8
        for (int kk = 0; kk < 64; ++kk) {
            float w0 = Wt0[kk][c2];
            float w1 = Wt1[kk][c2];
#pragma unroll
            for (int i = 0; i < 4; ++i) {
                float xv = xT[kk][r0 + i];
                acc[i][0] += xv * w0;
                acc[i][1] += xv * w1;
            }
        }
    }

    const int c0 = 2 * c2;
    const int headT = c0 >> 5, d0 = c0 & 31;
    const int b = rowBase >> 11;
    const int n0 = (rowBase & 2047) + r0;
    const int bh = b * 4 + headT;

    {   // V^T bf16, PRE-SWIZZLED within 256-j window: slot = gw ^ (d&7)
        ushort4 p0, p1;
        unsigned short* q0 = (unsigned short*)&p0;
        unsigned short* q1 = (unsigned short*)&p1;
#pragma unroll
        for (int i = 0; i < 4; ++i) {
            __hip_bfloat16 h0 = __float2bfloat16(acc[i][0]);
            __hip_bfloat16 h1 = __float2bfloat16(acc[i][1]);
            q0[i] = *(unsigned short*)&h0;
            q1[i] = *(unsigned short*)&h1;
        }
        const int wdw = n0 >> 8;
        const int gw  = (n0 >> 3) & 31;
        const int off = n0 & 7;
        const int gs0 = gw ^ (d0 & 7);
        const int gs1 = gw ^ ((d0 + 1) & 7);
        *(ushort4*)&VT[((size_t)bh * 32 + d0) * 2048 + wdw * WINJ + gs0 * 8 + off] = p0;
        *(ushort4*)&VT[((size_t)bh * 32 + d0 + 1) * 2048 + wdw * WINJ + gs1 * 8 + off] = p1;
    }
    {   // ei/ej (log2e-scaled)
        float a10 = a[headT * 64 + d0],      a11 = a[headT * 64 + d0 + 1];
        float a20 = a[headT * 64 + 32 + d0], a21 = a[headT * 64 + 32 + d0 + 1];
#pragma unroll
        for (int i = 0; i < 4; ++i) {
            float pi = acc[i][0] * a10 + acc[i][1] * a11;
            float pj = acc[i][0] * a20 + acc[i][1] * a21;
#pragma unroll
            for (int off = 1; off < 16; off <<= 1) {
                pi += __shfl_xor(pi, off);
                pj += __shfl_xor(pj, off);
            }
            if ((lane & 15) == 0) {
                ei_t[(size_t)bh * 2048 + n0 + i] = pi * LOG2E;
                ej_t[(size_t)bh * 2048 + n0 + i] = pj * LOG2E;
            }
        }
    }
}

// ---------- Kernel 2: MFMA attention, LDS windows + 2-way j-parity ----------
// grid 512 = b(4) x head(4) x rowtile(32 of 64 rows); block 512 thr = 8 waves =
// wtile(4 subtiles of 16 rows) x par(2 j-halves). Par p owns windows p*4..p*4+3
// in its own double-buffered LDS region. 2 blocks/CU -> 4 waves/SIMD.
__global__ __launch_bounds__(512) void k_attn_p(const unsigned short* __restrict__ VT,
                                                const float* __restrict__ ei_t,
                                                const float* __restrict__ ej_t,
                                                const unsigned long long* __restrict__ bitsT,
                                                float* __restrict__ out) {
    __shared__ __align__(16) unsigned short Vs[2][2][32 * WINJ];   // [par][buf] 4x16KB
    __shared__ __align__(16) float ejs[2][2][WINJ];                // 4x1KB

    const int tid = threadIdx.x;
    const int bid = blockIdx.x;
    const int rt = bid & 31;
    const int head = (bid >> 5) & 3;
    const int b = bid >> 7;
    const int wv = tid >> 6, lane = tid & 63;
    const int wtile = wv & 3, par = wv >> 2;
    const int lr = lane & 15;
    const int g = lane >> 4;
    const int rowW = rt * 64 + wtile * 16;
    const int bh = b * 4 + head;

    const unsigned short* VTb = VT + (size_t)bh * 32 * 2048;
    const float* ejg = ej_t + (size_t)bh * 2048;
    const float eir = ei_t[(size_t)bh * 2048 + rowW + lr];

    f32x4 acc0 = {0.f, 0.f, 0.f, 0.f};
    f32x4 acc1 = {0.f, 0.f, 0.f, 0.f};
    f32x4 accS = {0.f, 0.f, 0.f, 0.f};
    short8 onesb;
    {
        short ov = (lr == 0) ? (short)0x3F80 : (short)0;   // bf16 1.0 in col 0
#pragma unroll
        for (int e = 0; e < 8; ++e) onesb[e] = ov;
    }

    // ---- prologue: stage windows 0 (par0) and 4 (par1) ----
    {
#pragma unroll
        for (int p = 0; p < 2; ++p) {
            const unsigned short* src = VTb + (p * 4) * WINJ;
#pragma unroll
            for (int i = 0; i < 2; ++i) {
                int L = i * 512 + tid, d = L >> 5, gr = L & 31;
                float4 v = *(const float4*)&src[(size_t)d * 2048 + gr * 8];
                *(float4*)&Vs[p][0][(size_t)L * 8] = v;
            }
        }
        if (tid < 128) {
            int p = tid >> 6, idx = tid & 63;
            float4 e = *(const float4*)&ejg[(p * 4) * WINJ + idx * 4];
            *(float4*)&ejs[p][0][idx * 4] = e;
        }
    }
    __syncthreads();

    for (int t = 0; t < 4; ++t) {
        const int buf = t & 1;
        const int Wd = par * 4 + t;
        const unsigned long long wreg =
            bitsT[(size_t)(Wd * 4 + g) * 2048 + rowW + lr];

        float4 vr0, vr1, vr2, vr3, er;
        const bool pf = (t < 3);
        if (pf) {   // issue next windows' loads EARLY (both parities)
            const unsigned short* s0 = VTb + (t + 1) * WINJ;
            const unsigned short* s1 = VTb + (5 + t) * WINJ;
            int L0 = tid, d0_ = L0 >> 5, g0_ = L0 & 31;
            int L1 = 512 + tid, d1_ = L1 >> 5, g1_ = L1 & 31;
            vr0 = *(const float4*)&s0[(size_t)d0_ * 2048 + g0_ * 8];
            vr1 = *(const float4*)&s0[(size_t)d1_ * 2048 + g1_ * 8];
            vr2 = *(const float4*)&s1[(size_t)d0_ * 2048 + g0_ * 8];
            vr3 = *(const float4*)&s1[(size_t)d1_ * 2048 + g1_ * 8];
            if (tid < 128) {
                int p = tid >> 6, idx = tid & 63;
                er = *(const float4*)&ejg[(p ? (5 + t) : (t + 1)) * WINJ + idx * 4];
            }
        }
        __builtin_amdgcn_sched_barrier(0);   // pin load issue before compute

        const unsigned short* Vb = &Vs[par][buf][0];
        const float* ejb = &ejs[par][buf][0];
#pragma unroll
        for (int jl = 0; jl < WINJ; jl += 64) {
            const unsigned long long word = __shfl(wreg, (jl >> 6) * 16 + lr);
#pragma unroll
            for (int ks = 0; ks < 2; ++ks) {
                const int gw_ = (jl >> 3) + ks * 4 + g;
                const int slot = gw_ ^ (lr & 7);
                short8 b0 = *(const short8*)&Vb[lr * WINJ + slot * 8];
                short8 b1 = *(const short8*)&Vb[(16 + lr) * WINJ + slot * 8];
                const int f = jl + ks * 32 + g * 8;
                float4 ea = *(const float4*)&ejb[f];
                float4 eb = *(const float4*)&ejb[f + 4];
                const unsigned int mb =
                    (unsigned int)(word >> (ks * 32 + g * 8)) & 0xffu;
                float ej8[8] = {ea.x, ea.y, ea.z, ea.w, eb.x, eb.y, eb.z, eb.w};
                short8 pa;
#pragma unroll
                for (int e = 0; e < 8; ++e) {
                    float s = eir + ej8[e];                  // log2-domain score
                    float el = fmaxf(s, NEG * s);            // exact leaky-relu
                    float p = ((mb >> e) & 1u) ? __builtin_amdgcn_exp2f(el) : 0.f;
                    __hip_bfloat16 pb = __float2bfloat16(p);
                    pa[e] = (short)*(unsigned short*)&pb;
                }
                __builtin_amdgcn_s_setprio(1);
                acc0 = __builtin_amdgcn_mfma_f32_16x16x32_bf16(pa, b0, acc0, 0, 0, 0);
                acc1 = __builtin_amdgcn_mfma_f32_16x16x32_bf16(pa, b1, acc1, 0, 0, 0);
                accS = __builtin_amdgcn_mfma_f32_16x16x32_bf16(pa, onesb, accS, 0, 0, 0);
                __builtin_amdgcn_s_setprio(0);
            }
        }

        if (pf) {   // write-late into the other buffers
            const int nb = buf ^ 1;
            *(float4*)&Vs[0][nb][(size_t)tid * 8]         = vr0;
            *(float4*)&Vs[0][nb][(size_t)(512 + tid) * 8] = vr1;
            *(float4*)&Vs[1][nb][(size_t)tid * 8]         = vr2;
            *(float4*)&Vs[1][nb][(size_t)(512 + tid) * 8] = vr3;
            if (tid < 128) {
                int p = tid >> 6, idx = tid & 63;
                *(float4*)&ejs[p][nb][idx * 4] = er;
            }
        }
        __syncthreads();
    }

    // ---- combine parities via LDS scratch (aliases Vs[0][0], done with windows) ----
    float* redf = (float*)&Vs[0][0][0];   // 4 wtiles x 64 lanes x 13 floats = 13KB
    if (par == 1) {
        float* r = &redf[(wtile * 64 + lane) * 13];
#pragma unroll
        for (int q = 0; q < 4; ++q) {
            r[q] = acc0[q]; r[4 + q] = acc1[q]; r[8 + q] = accS[q];
        }
    }
    __syncthreads();
    if (par == 0) {
        const float* r = &redf[(wtile * 64 + lane) * 13];
#pragma unroll
        for (int q = 0; q < 4; ++q) {
            acc0[q] += r[q]; acc1[q] += r[4 + q]; accS[q] += r[8 + q];
        }
        // C/D layout (HW-verified): col = lane&15, row = 4*(lane>>4)+reg.
#pragma unroll
        for (int reg = 0; reg < 4; ++reg) {
            const float sr = __shfl(accS[reg], g * 16);
            const float inv = 1.f / sr;
            const int m = 4 * g + reg;
            float* dst = &out[(size_t)(b * N + rowW + m) * 128 + head * 32 + lr];
            dst[0]  = acc0[reg] * inv;
            dst[16] = acc1[reg] * inv;
        }
    }
}

// ================= FALLBACK: ZERO-WORKSPACE FUSED KERNEL =================
__global__ __launch_bounds__(256) void k_fused(const float* __restrict__ x,
                                               const int* __restrict__ adj,
                                               const float* __restrict__ W,
                                               const float* __restrict__ a,
                                               float* __restrict__ out) {
    __shared__ float Ws[32][129];
    __shared__ float xs[64][132];
    __shared__ float hs[64][44];
    __shared__ float ejs[64];
    __shared__ float eis[128];
    __shared__ float a1s[32], a2s[32];
    __shared__ unsigned long long mb[128];

    const int tid = threadIdx.x;
    const int bid = blockIdx.x;
    const int rt = bid & 15;
    const int head = (bid >> 4) & 3;
    const int b = bid >> 6;
    const int row0 = rt * 128;

    for (int idx = tid; idx < 32 * 128; idx += 256) {
        int d = idx >> 7, k = idx & 127;
        Ws[d][k] = W[(head * 32 + d) * 128 + k];
    }
    if (tid < 32) a1s[tid] = a[head * 64 + tid];
    else if (tid < 64) a2s[tid - 32] = a[head * 64 + tid];
    __syncthreads();

    for (int c0 = 0; c0 < 128; c0 += 64) {
        __syncthreads();
        {
            int jj = tid >> 2, k0 = (tid & 3) * 32;
            const float4* src = (const float4*)&x[(b * N + row0 + c0 + jj) * 128 + k0];
#pragma unroll
            for (int q = 0; q < 8; ++q) *(float4*)&xs[jj][k0 + q * 4] = src[q];
        }
        __syncthreads();
        {
            int jj = tid >> 2, db = (tid & 3) * 8;
#pragma unroll
            for (int dd = 0; dd < 8; ++dd) {
                float s = 0.f;
                for (int k = 0; k < 128; ++k) s += xs[jj][k] * Ws[db + dd][k];
                hs[jj][db + dd] = s;
            }
        }
        __syncthreads();
        if (tid < 64) {
            float s = 0.f;
#pragma unroll
            for (int d = 0; d < 32; ++d) s += hs[tid][d] * a1s[d];
            eis[c0 + tid] = s;
        }
    }

    const int dgrp = tid & 3, d0 = dgrp * 8;
    const int rseg = tid >> 2;
    float acc[2][8];
    float sacc[2] = {0.f, 0.f};
#pragma unroll
    for (int k = 0; k < 2; ++k)
#pragma unroll
        for (int d = 0; d < 8; ++d) acc[k][d] = 0.f;

    for (int jc = 0; jc < N; jc += 64) {
        __syncthreads();
        {
            int jj = tid >> 2, k0 = (tid & 3) * 32;
            const float4* src = (const float4*)&x[(b * N + jc + jj) * 128 + k0];
#pragma unroll
            for (int q = 0; q < 8; ++q) *(float4*)&xs[jj][k0 + q * 4] = src[q];
        }
        {
            int wv = tid >> 6, lane = tid & 63;
            for (int p = 0; p < 32; ++p) {
                int il = p * 4 + wv;
                unsigned long long m = __ballot(adj[(row0 + il) * N + jc + lane] != 0);
                if (lane == 0) mb[il] = m;
            }
        }
        __syncthreads();
        {
            int jj = tid >> 2, db = (tid & 3) * 8;
#pragma unroll
            for (int dd = 0; dd < 8; ++dd) {
                float s = 0.f;
                for (int k = 0; k < 128; ++k) s += xs[jj][k] * Ws[db + dd][k];
                hs[jj][db + dd] = s;
            }
        }
        __syncthreads();
        if (tid < 64) {
            float s = 0.f;
#pragma unroll
            for (int d = 0; d < 32; ++d) s += hs[tid][d] * a2s[d];
            ejs[tid] = s;
        }
        __syncthreads();
        for (int jj = 0; jj < 64; ++jj) {
            float ejv = ejs[jj];
            float hv[8];
#pragma unroll
            for (int d = 0; d < 8; ++d) hv[d] = hs[jj][d0 + d];
#pragma unroll
            for (int k = 0; k < 2; ++k) {
                int il = rseg * 2 + k;
                float s = eis[il] + ejv;
                float el = s > 0.f ? s : NEG * s;
                float p = ((mb[il] >> jj) & 1ull) ? __expf(el) : 0.f;
                sacc[k] += p;
#pragma unroll
                for (int d = 0; d < 8; ++d) acc[k][d] += p * hv[d];
            }
        }
    }
#pragma unroll
    for (int k = 0; k < 2; ++k) {
        int il = rseg * 2 + k;
        float inv = 1.f / sacc[k];
        float* dst = &out[(b * N + row0 + il) * 128 + head * 32 + d0];
#pragma unroll
        for (int d = 0; d < 8; ++d) dst[d] = acc[k][d] * inv;
    }
}

extern "C" void kernel_launch(void* const* d_in, const int* in_sizes, int n_in,
                              void* d_out, int out_size, void* d_ws, size_t ws_size,
                              hipStream_t stream) {
    // Identify inputs by element count (all unique) — order-proof.
    const float* x = nullptr; const int* adj = nullptr;
    const float* W = nullptr; const float* a = nullptr;
    for (int i = 0; i < n_in; ++i) {
        switch (in_sizes[i]) {
            case B * N * DIN:  x   = (const float*)d_in[i]; break;  // 1048576
            case N * N:        adj = (const int*)d_in[i];   break;  // 4194304
            case H * HD * DIN: W   = (const float*)d_in[i]; break;  // 16384
            case H * 2 * HD:   a   = (const float*)d_in[i]; break;  // 256
        }
    }
    float* out = (float*)d_out;   // reference output dtype is float32

    // ws: VT bf16 2MB | ei_t 128KB | ej_t 128KB | bitsT 512KB  = 2.75 MB
    const size_t szVT = (size_t)B * H * HD * N * 2;
    const size_t szE  = (size_t)B * H * N * 4;
    const size_t szBits = (size_t)N * (N / 64) * 8;
    const size_t need = szVT + 2 * szE + szBits;

    if (ws_size >= need) {
        char* ws = (char*)d_ws;
        unsigned short* VT = (unsigned short*)ws;
        float* ei_t = (float*)(ws + szVT);
        float* ej_t = (float*)(ws + szVT + szE);
        unsigned long long* bitsT = (unsigned long long*)(ws + szVT + 2 * szE);

        k_prep<<<512, 256, 0, stream>>>(x, W, a, adj, VT, ei_t, ej_t, bitsT);
        k_attn_p<<<512, 512, 0, stream>>>(VT, ei_t, ej_t, bitsT, out);
    } else {
        k_fused<<<256, 256, 0, stream>>>(x, adj, W, a, out);
    }
}